// Round 7
// baseline (226.535 us; speedup 1.0000x reference)
//
#include <hip/hip_runtime.h>
#include <math.h>

typedef __bf16 bf16_t;
typedef __bf16 bf16x8 __attribute__((ext_vector_type(8)));
typedef __bf16 bf16x4 __attribute__((ext_vector_type(4)));
typedef short short4v __attribute__((ext_vector_type(4)));
typedef float f32x4 __attribute__((ext_vector_type(4)));

#define LOG2E 1.4426950408889634f

#if __has_builtin(__builtin_amdgcn_exp2f)
#define FAST_EXP2(x) __builtin_amdgcn_exp2f(x)
#else
#define FAST_EXP2(x) exp2f(x)
#endif

#define GLOBAL_AS __attribute__((address_space(1)))
#define LDS_AS    __attribute__((address_space(3)))

// async 16B/lane global->LDS DMA: lane i's data lands at ldsbase + i*16.
__device__ __forceinline__ void async_ld16(const void* g, void* l) {
    __builtin_amdgcn_global_load_lds((const GLOBAL_AS void*)g,
                                     (LDS_AS void*)l, 16, 0, 0);
}

constexpr int BATCH = 4;
constexpr int SEQ = 2048;
constexpr int NHEADS = 16;
constexpr int DK = 64;
constexpr int DMODEL = 1024;
constexpr int NTOK = BATCH * SEQ;  // 8192

// workspace layout (bytes)
constexpr size_t WT_OFF   = 0;                                   // 3*16*64*64 bf16
constexpr size_t BIAS_OFF = WT_OFF + (size_t)3*16*64*64*2;
constexpr size_t Q_OFF    = BIAS_OFF + (size_t)3*16*64*4;
constexpr size_t QSZ      = (size_t)BATCH*NHEADS*SEQ*DK*2;
constexpr size_t K_OFF    = Q_OFF + QSZ;
constexpr size_t VT_OFF   = K_OFF + QSZ;
constexpr size_t O_OFF    = VT_OFF + QSZ;

// ---------------------------------------------------------------------------
// Kernel 0: weight prep.  Wt[p][h][e][d] = W_p[h][d][e].
// Q path additionally scaled by LOG2E/8 so flash can exp2() raw MFMA output.
// ---------------------------------------------------------------------------
__global__ __launch_bounds__(256) void prep_kernel(
    const float* __restrict__ Wq, const float* __restrict__ Wk,
    const float* __restrict__ Wv, const float* __restrict__ bq,
    const float* __restrict__ bk, const float* __restrict__ bv,
    bf16_t* __restrict__ Wt, float* __restrict__ bias)
{
    const float QS = 0.125f * LOG2E;
    int i = blockIdx.x * 256 + threadIdx.x;
    if (i < 3*16*64*64) {
        int d = i & 63, e = (i >> 6) & 63, h = (i >> 12) & 15, p = i >> 16;
        const float* W = (p == 0) ? Wq : (p == 1) ? Wk : Wv;
        float v = W[(h*64 + d)*64 + e] * ((p == 0) ? QS : 1.0f);
        Wt[i] = (bf16_t)v;
    }
    if (i < 3*16*64) {
        int e = i & 63, h = (i >> 6) & 15, p = i >> 10;
        const float* bb = (p == 0) ? bq : (p == 1) ? bk : bv;
        bias[i] = bb[h*64 + e] * ((p == 0) ? QS : 1.0f);
    }
}

// ---------------------------------------------------------------------------
// Kernel 1: QKV projection.  One wave = 16 tokens x 1 head x {Q,K,V}.
// R13: block's 4 waves share one 16-token tile across 4 adjacent heads;
// x slab staged through LDS with coalesced float4 loads.
// V stored transposed [b][h][dk][s] with the in-block-of-32 key permutation
// (R9) AND (R14) a per-e-row slot XOR: logical key-group i2 of e-row e is
// stored at slot i2 ^ ((e>>1)&3).  Flash reads with the same XOR -> its
// 16-lane PV reads spread across 8 bank-groups (2-way = free) despite the
// 64B V rows of the 32-key chunk format.
// ---------------------------------------------------------------------------
__global__ __launch_bounds__(256) void qkv_kernel(
    const float* __restrict__ x, const bf16_t* __restrict__ Wt,
    const float* __restrict__ bias,
    bf16_t* __restrict__ Q, bf16_t* __restrict__ Kg, bf16_t* __restrict__ Vt)
{
    constexpr int QSTR = 72;   // 144 B row stride: 16B-aligned, conflict-free
    constexpr int XSTR = 264;  // 16-row x-slab stride: 528B -> 2-way alias only
    __shared__ bf16_t Xlds[16 * XSTR];     // 8.25 KB
    __shared__ bf16_t Slds[4][16 * QSTR];  // 9 KB
    const int tid = threadIdx.x;
    const int w = tid >> 6, lane = tid & 63;
    const int ln = lane & 15, quad = lane >> 4;
    const int bid = blockIdx.x;
    const int t0 = (bid >> 2) * 16;        // token tile (shared by block)
    const int h0 = (bid & 3) * 4;          // first head of this block
    const int h  = h0 + w;                 // this wave's head
    const int b = t0 >> 11;
    const int s0 = t0 & 2047;
    const int bh = b * 16 + h;

    // ---- coalesced x staging: 16 rows x 256 floats -> bf16 LDS slab
#pragma unroll
    for (int i = 0; i < 4; i++) {
        const int idx = i * 256 + tid;     // 0..1023
        const int row = idx >> 6;          // 0..15
        const int c4  = idx & 63;          // float4 index within 256-float span
        float4 u = *(const float4*)&x[(size_t)(t0 + row)*DMODEL + h0*64 + c4*4];
        bf16x4 v4;
        v4[0] = (bf16_t)u.x; v4[1] = (bf16_t)u.y;
        v4[2] = (bf16_t)u.z; v4[3] = (bf16_t)u.w;
        *(bf16x4*)&Xlds[row*XSTR + c4*4] = v4;
    }
    __syncthreads();

    // A-fragments from LDS: A[m=ln][k=quad*8+j], k-chunks of 32.
    bf16x8 afrag[2];
#pragma unroll
    for (int kc = 0; kc < 2; kc++)
        afrag[kc] = *(const bf16x8*)&Xlds[ln*XSTR + w*64 + kc*32 + quad*8];

#pragma unroll
    for (int p = 0; p < 3; p++) {
#pragma unroll
        for (int nt = 0; nt < 4; nt++) {
            const bf16_t* wp = &Wt[((size_t)((p*16 + h)*64) + nt*16 + ln)*64 + quad*8];
            bf16x8 b0 = *(const bf16x8*)wp;
            bf16x8 b1 = *(const bf16x8*)(wp + 32);
            f32x4 acc = {0.f, 0.f, 0.f, 0.f};
            acc = __builtin_amdgcn_mfma_f32_16x16x32_bf16(afrag[0], b0, acc, 0, 0, 0);
            acc = __builtin_amdgcn_mfma_f32_16x16x32_bf16(afrag[1], b1, acc, 0, 0, 0);
            float bv = bias[(p*16 + h)*64 + nt*16 + ln];
#pragma unroll
            for (int r = 0; r < 4; r++)
                Slds[w][(quad*4 + r)*QSTR + nt*16 + ln] = (bf16_t)(acc[r] + bv);
        }
        if (p < 2) {
            // row-major coalesced writeout: lane -> (row=lane>>2, col=(lane&3)*16)
            bf16_t* dst = (p == 0) ? Q : Kg;
            const int row = lane >> 2, c = (lane & 3) * 16;
            bf16_t* dp = &dst[((size_t)bh*SEQ + s0 + row)*DK + c];
            *(uint4*)dp       = *(const uint4*)&Slds[w][row*QSTR + c];
            *(uint4*)(dp + 8) = *(const uint4*)&Slds[w][row*QSTR + c + 8];
        } else {
            // V^T writeout: lane = e (0..63), pack 16 tokens (column), with
            // the in-block-of-32 permutation + R14 per-e-row slot XOR.
            unsigned int packed[8];
#pragma unroll
            for (int i = 0; i < 8; i++) {
                unsigned short lo = __builtin_bit_cast(unsigned short, Slds[w][(2*i  )*QSTR + lane]);
                unsigned short hi = __builtin_bit_cast(unsigned short, Slds[w][(2*i+1)*QSTR + lane]);
                packed[i] = (unsigned)lo | ((unsigned)hi << 16);
            }
            const int base32 = s0 & ~31;          // 32-key block base
            const int pr = (s0 >> 4) & 1;         // which 16-half of the block
            const int f  = (lane >> 1) & 3;       // per-e-row slot XOR (R14)
            unsigned* vp32 = (unsigned*)&Vt[((size_t)bh*DK + lane)*SEQ + base32];
#pragma unroll
            for (int i2 = 0; i2 < 4; i2++) {
                uint2 u; u.x = packed[2*i2]; u.y = packed[2*i2 + 1];
                *(uint2*)(vp32 + ((i2 ^ f) << 2) + pr*2) = u;
            }
        }
    }
}

// ---------------------------------------------------------------------------
// Kernel 2: flash attention.  R14: CONCURRENCY restructure.
// R6-R13 counters showed MFMA/VALU/LDS all balanced at ~45% with the 4-wave
// 128q/64k lockstep block -- the serial QKT->SM->PV chain leaves each pipe
// half-idle, and register-carried pipelining (R10-R12) always spilled.
// Fix via TLP instead: block = 2 waves x 32 queries, chunk = 32 keys,
// LDS 16 KB -> 8 blocks/CU (was 4), grid 2048.  Eight independent blocks
// per CU sit at different phases, overlapping each other's barrier stalls.
//   - K LDS: 32 rows x 128B, same 8-row-group staging swizzle (conflict-free)
//   - V LDS: 64 rows x 64B; slot XOR f(e)=(e>>1)&3 pre-applied in global
//     (qkv R14) -> PV 16-lane reads 2-way only.
//   - same 16x16x32 MFMAs, same permuted-k PV, same accumulation order.
// ---------------------------------------------------------------------------
__global__ __launch_bounds__(128, 4) void flash_kernel(
    const bf16_t* __restrict__ Q, const bf16_t* __restrict__ Kg,
    const bf16_t* __restrict__ Vt, bf16_t* __restrict__ O)
{
    __shared__ union {
        struct { bf16_t K[2][32*64]; bf16_t V[2][64*32]; } kv;  // 16 KB
        bf16_t O[2][32 * 72];        // epilogue reuse (after barrier)
    } sh;

    const int tid = threadIdx.x;
    const int w = tid >> 6, lane = tid & 63;   // w in {0,1}
    const int ln = lane & 15, quad = lane >> 4;
    // XCD swizzle: all 32 q-tiles of one bh on one XCD; 8 bh per XCD -> K/V
    // working set 4MB = L2 size.  2048 % 8 == 0 -> bijective.
    const int bid = blockIdx.x;
    const int xcd = bid & 7;
    const int j   = bid >> 3;            // 0..255
    const int bh  = xcd * 8 + (j & 7);   // 0..63
    const int qt  = j >> 3;              // 0..31
    const int q0 = qt * 64 + w * 32;

    const bf16_t* kbase = &Kg[(size_t)bh * SEQ * DK];
    const bf16_t* vbase = &Vt[(size_t)bh * DK * SEQ];

    // staging coords.  K: wave w covers rows w*16..w*16+15 (2 issues x 8 rows,
    // swizzled 16B slots).  V: wave w covers e-rows w*32..w*32+31 (2 issues x
    // 16 rows of 64B, linear slots -- global already pre-swizzled).
    const int lrow = lane >> 3;               // 0..7
    const int swz  = ((lane & 7) ^ lrow) * 8; // K stage swizzle (elem offset)
    const int vrow = lane >> 2;               // 0..15
    const int vsl  = (lane & 3) * 8;          // V stage slot (elem offset)

    auto stage = [&](int ci, int buf) {
#pragma unroll
        for (int jj = 0; jj < 2; jj++) {
            const int rk = w*16 + jj*8 + lrow;      // K tile row, rk&7 == lrow
            async_ld16(&kbase[(size_t)(ci*32 + rk)*DK + swz],
                       &sh.kv.K[buf][(w*16 + jj*8)*64]);
            const int rv = w*32 + jj*16 + vrow;     // V e-row
            async_ld16(&vbase[(size_t)rv*SEQ + ci*32 + vsl],
                       &sh.kv.V[buf][(w*32 + jj*16)*32]);
        }
    };

    // Resident Q B-fragments: B[k=d=quad*8+j][n=i=ln] = Q[i][d]
    bf16x8 qfrag[2][2];
#pragma unroll
    for (int st = 0; st < 2; st++)
#pragma unroll
        for (int kc = 0; kc < 2; kc++)
            qfrag[st][kc] = *(const bf16x8*)
                &Q[((size_t)bh*SEQ + q0 + st*16 + ln)*DK + kc*32 + quad*8];

    f32x4 o[2][4];
#pragma unroll
    for (int st = 0; st < 2; st++)
#pragma unroll
        for (int dt = 0; dt < 4; dt++)
            o[st][dt] = (f32x4){0.f, 0.f, 0.f, 0.f};
    float l_[2] = {0.f, 0.f};

    // per-lane swizzle constants for fragment reads
    const int s7    = ln & 7;
    const int kc0   = (quad ^ s7) * 8;          // QKT ka0 offset; ka1 = kc0^32
    const int vslot = (quad ^ ((ln >> 1) & 3)) * 8;  // PV slot (R14 XOR)

    constexpr int NC = SEQ / 32;  // 64 chunks of 32 keys
    stage(0, 0);

#pragma unroll 2
    for (int ci = 0; ci < NC; ci++) {
        // chunk-ci loads were issued a full compute-section ago
        asm volatile("s_waitcnt vmcnt(0)" ::: "memory");
        __syncthreads();
        if (ci + 1 < NC) stage(ci + 1, (ci + 1) & 1);

        const bf16_t* Kb = sh.kv.K[ci & 1];
        const bf16_t* Vb = sh.kv.V[ci & 1];

        // S^T = K * Q^T : rows = keys (32), cols = queries
        f32x4 sfrag[2][2];
#pragma unroll
        for (int kt = 0; kt < 2; kt++) {
            const int kr = (kt*16 + ln) * 64;
            bf16x8 ka0 = *(const bf16x8*)&Kb[kr + kc0];
            bf16x8 ka1 = *(const bf16x8*)&Kb[kr + (kc0 ^ 32)];
#pragma unroll
            for (int st = 0; st < 2; st++) {
                f32x4 acc = {0.f, 0.f, 0.f, 0.f};
                acc = __builtin_amdgcn_mfma_f32_16x16x32_bf16(ka0, qfrag[st][0], acc, 0, 0, 0);
                acc = __builtin_amdgcn_mfma_f32_16x16x32_bf16(ka1, qfrag[st][1], acc, 0, 0, 0);
                sfrag[st][kt] = acc;
            }
        }

        // P = exp2(S^T); l += per-lane sums (VALU); perm-pack into ONE K=32
        // B-fragment per st (permuted k-axis: slot (quad,j) <-> key
        // (j>>2)*16 + quad*4 + (j&3) -- all lane-local).
        bf16x8 pfrag[2];
#pragma unroll
        for (int st = 0; st < 2; st++) {
            float sum = 0.f;
            unsigned pk[4];
#pragma unroll
            for (int kt = 0; kt < 2; kt++) {
                float e0 = FAST_EXP2(sfrag[st][kt][0]);
                float e1 = FAST_EXP2(sfrag[st][kt][1]);
                float e2 = FAST_EXP2(sfrag[st][kt][2]);
                float e3 = FAST_EXP2(sfrag[st][kt][3]);
                sum += (e0 + e1) + (e2 + e3);
                unsigned u0 = __builtin_bit_cast(unsigned, e0);
                unsigned u1 = __builtin_bit_cast(unsigned, e1);
                unsigned u2 = __builtin_bit_cast(unsigned, e2);
                unsigned u3 = __builtin_bit_cast(unsigned, e3);
                pk[2*kt]     = __builtin_amdgcn_perm(u1, u0, 0x07060302);
                pk[2*kt + 1] = __builtin_amdgcn_perm(u3, u2, 0x07060302);
            }
            l_[st] += sum;
            uint4 lo; lo.x = pk[0]; lo.y = pk[1]; lo.z = pk[2]; lo.w = pk[3];
            pfrag[st] = __builtin_bit_cast(bf16x8, lo);
        }

        // O^T += V^T * P^T (16x16x32, permuted k; V pre-permuted+slot-XOR'd
        // in global so each A-fragment is ONE contiguous b128)
        __builtin_amdgcn_s_setprio(1);
#pragma unroll
        for (int dt = 0; dt < 4; dt++) {
            const int vr = (dt*16 + ln) * 32;
            bf16x8 va = *(const bf16x8*)&Vb[vr + vslot];
            o[0][dt] = __builtin_amdgcn_mfma_f32_16x16x32_bf16(
                va, pfrag[0], o[0][dt], 0, 0, 0);
            o[1][dt] = __builtin_amdgcn_mfma_f32_16x16x32_bf16(
                va, pfrag[1], o[1][dt], 0, 0, 0);
        }
        __builtin_amdgcn_s_setprio(0);
    }

    // epilogue: reduce l across quads, normalize, transpose via LDS (reuses
    // the K/V buffers -- barrier first), coalesced store
    __syncthreads();
#pragma unroll
    for (int st = 0; st < 2; st++) {
        float l = l_[st];
        l += __shfl_xor(l, 16);
        l += __shfl_xor(l, 32);
        float rl = 1.0f / l;
#pragma unroll
        for (int dt = 0; dt < 4; dt++)
#pragma unroll
            for (int r = 0; r < 4; r++)
                sh.O[w][(st*16 + ln)*72 + dt*16 + quad*4 + r] =
                    (bf16_t)(o[st][dt][r] * rl);
    }
    const int token = lane >> 1, half = lane & 1;
    const int b = bh >> 4, h = bh & 15;
    const size_t s = (size_t)q0 + token;
    bf16_t* op = &O[(((size_t)b*SEQ + s)*NHEADS + h)*DK + half*32];
#pragma unroll
    for (int k2 = 0; k2 < 4; k2++)
        *(uint4*)(op + k2*8) = *(const uint4*)&sh.O[w][token*72 + half*32 + k2*8];
}

// ---------------------------------------------------------------------------
// Kernel 3: residual + LayerNorm.  One wave per token.
// ---------------------------------------------------------------------------
__global__ __launch_bounds__(256) void ln_kernel(
    const bf16_t* __restrict__ O, const float* __restrict__ x,
    const float* __restrict__ gamma, const float* __restrict__ beta,
    float* __restrict__ out)
{
    const int tid = threadIdx.x;
    const int w = tid >> 6, lane = tid & 63;
    const size_t t = (size_t)blockIdx.x * 4 + w;
    const int d0 = lane * 16;
    const bf16_t* op = &O[t*DMODEL + d0];
    const float* xp = &x[t*DMODEL + d0];

    bf16x8 oa = *(const bf16x8*)op;
    bf16x8 ob = *(const bf16x8*)(op + 8);
    float xs[16];
    ((float4*)xs)[0] = *(const float4*)(xp);
    ((float4*)xs)[1] = *(const float4*)(xp + 4);
    ((float4*)xs)[2] = *(const float4*)(xp + 8);
    ((float4*)xs)[3] = *(const float4*)(xp + 12);

    float yv[16];
    float sum = 0.f, sq = 0.f;
#pragma unroll
    for (int j = 0; j < 16; j++) {
        float ov = (j < 8) ? (float)oa[j] : (float)ob[j - 8];
        yv[j] = ov + xs[j];
        sum += yv[j];
        sq += yv[j] * yv[j];
    }
#pragma unroll
    for (int off = 1; off < 64; off <<= 1) {
        sum += __shfl_xor(sum, off);
        sq  += __shfl_xor(sq, off);
    }
    float mean = sum * (1.0f / DMODEL);
    float var = sq * (1.0f / DMODEL) - mean * mean;
    float rstd = rsqrtf(var + 1e-5f);

    float gs[16], bs[16];
    ((float4*)gs)[0] = *(const float4*)&gamma[d0];
    ((float4*)gs)[1] = *(const float4*)&gamma[d0 + 4];
    ((float4*)gs)[2] = *(const float4*)&gamma[d0 + 8];
    ((float4*)gs)[3] = *(const float4*)&gamma[d0 + 12];
    ((float4*)bs)[0] = *(const float4*)&beta[d0];
    ((float4*)bs)[1] = *(const float4*)&beta[d0 + 4];
    ((float4*)bs)[2] = *(const float4*)&beta[d0 + 8];
    ((float4*)bs)[3] = *(const float4*)&beta[d0 + 12];

    float res[16];
#pragma unroll
    for (int j = 0; j < 16; j++)
        res[j] = (yv[j] - mean) * rstd * gs[j] + bs[j];
    float* outp = &out[t*DMODEL + d0];
    *(float4*)(outp)      = *(float4*)&res[0];
    *(float4*)(outp + 4)  = *(float4*)&res[4];
    *(float4*)(outp + 8)  = *(float4*)&res[8];
    *(float4*)(outp + 12) = *(float4*)&res[12];
}

// ---------------------------------------------------------------------------
extern "C" void kernel_launch(void* const* d_in, const int* in_sizes, int n_in,
                              void* d_out, int out_size, void* d_ws, size_t ws_size,
                              hipStream_t stream) {
    const float* x     = (const float*)d_in[0];
    const float* Wq    = (const float*)d_in[1];
    const float* Wk    = (const float*)d_in[2];
    const float* Wv    = (const float*)d_in[3];
    const float* bq    = (const float*)d_in[4];
    const float* bk    = (const float*)d_in[5];
    const float* bv    = (const float*)d_in[6];
    const float* gamma = (const float*)d_in[7];
    const float* beta  = (const float*)d_in[8];

    char* ws = (char*)d_ws;
    bf16_t* Wt   = (bf16_t*)(ws + WT_OFF);
    float*  bias = (float*)(ws + BIAS_OFF);
    bf16_t* Qb   = (bf16_t*)(ws + Q_OFF);
    bf16_t* Kb   = (bf16_t*)(ws + K_OFF);
    bf16_t* Vtb  = (bf16_t*)(ws + VT_OFF);
    bf16_t* Ob   = (bf16_t*)(ws + O_OFF);

    prep_kernel<<<768, 256, 0, stream>>>(Wq, Wk, Wv, bq, bk, bv, Wt, bias);
    qkv_kernel<<<NTOK*NHEADS/16/4, 256, 0, stream>>>(x, Wt, bias, Qb, Kb, Vtb);
    flash_kernel<<<BATCH*NHEADS*(SEQ/64), 128, 0, stream>>>(Qb, Kb, Vtb, Ob);
    ln_kernel<<<NTOK/4, 256, 0, stream>>>(Ob, x, gamma, beta, (float*)d_out);
}

// Round 8
// 218.476 us; speedup vs baseline: 1.0369x; 1.0369x over previous
//
#include <hip/hip_runtime.h>
#include <math.h>

typedef __bf16 bf16_t;
typedef __bf16 bf16x8 __attribute__((ext_vector_type(8)));
typedef __bf16 bf16x4 __attribute__((ext_vector_type(4)));
typedef short short4v __attribute__((ext_vector_type(4)));
typedef float f32x4 __attribute__((ext_vector_type(4)));

#define LOG2E 1.4426950408889634f

#if __has_builtin(__builtin_amdgcn_exp2f)
#define FAST_EXP2(x) __builtin_amdgcn_exp2f(x)
#else
#define FAST_EXP2(x) exp2f(x)
#endif

#define GLOBAL_AS __attribute__((address_space(1)))
#define LDS_AS    __attribute__((address_space(3)))

// async 16B/lane global->LDS DMA: lane i's data lands at ldsbase + i*16.
__device__ __forceinline__ void async_ld16(const void* g, void* l) {
    __builtin_amdgcn_global_load_lds((const GLOBAL_AS void*)g,
                                     (LDS_AS void*)l, 16, 0, 0);
}

constexpr int BATCH = 4;
constexpr int SEQ = 2048;
constexpr int NHEADS = 16;
constexpr int DK = 64;
constexpr int DMODEL = 1024;
constexpr int NTOK = BATCH * SEQ;  // 8192

// workspace layout (bytes)
constexpr size_t WT_OFF   = 0;                                   // 3*16*64*64 bf16
constexpr size_t BIAS_OFF = WT_OFF + (size_t)3*16*64*64*2;
constexpr size_t Q_OFF    = BIAS_OFF + (size_t)3*16*64*4;
constexpr size_t QSZ      = (size_t)BATCH*NHEADS*SEQ*DK*2;
constexpr size_t K_OFF    = Q_OFF + QSZ;
constexpr size_t VT_OFF   = K_OFF + QSZ;
constexpr size_t O_OFF    = VT_OFF + QSZ;

// ---------------------------------------------------------------------------
// Kernel 0: weight prep.  Wt[p][h][e][d] = W_p[h][d][e].
// Q path additionally scaled by LOG2E/8 so flash can exp2() raw MFMA output.
// ---------------------------------------------------------------------------
__global__ __launch_bounds__(256) void prep_kernel(
    const float* __restrict__ Wq, const float* __restrict__ Wk,
    const float* __restrict__ Wv, const float* __restrict__ bq,
    const float* __restrict__ bk, const float* __restrict__ bv,
    bf16_t* __restrict__ Wt, float* __restrict__ bias)
{
    const float QS = 0.125f * LOG2E;
    int i = blockIdx.x * 256 + threadIdx.x;
    if (i < 3*16*64*64) {
        int d = i & 63, e = (i >> 6) & 63, h = (i >> 12) & 15, p = i >> 16;
        const float* W = (p == 0) ? Wq : (p == 1) ? Wk : Wv;
        float v = W[(h*64 + d)*64 + e] * ((p == 0) ? QS : 1.0f);
        Wt[i] = (bf16_t)v;
    }
    if (i < 3*16*64) {
        int e = i & 63, h = (i >> 6) & 15, p = i >> 10;
        const float* bb = (p == 0) ? bq : (p == 1) ? bk : bv;
        bias[i] = bb[h*64 + e] * ((p == 0) ? QS : 1.0f);
    }
}

// ---------------------------------------------------------------------------
// Kernel 1: QKV projection.
// R15: TLP restructure.  Old grid was 512 blocks (2 blocks/CU, 8 waves/CU)
// -- a latency-bound straggler hiding in the ~138us non-flash lump.  New:
// block = 64 tokens x ONE head (grid 128 x 16 = 2048 blocks = 8 blocks/CU
// = 32 waves/CU).  Per-wave work unchanged: 16 tokens x {Q,K,V}.
// x staged as the block's 64x64 head-slice (rows = 256B contiguous segs).
// Q,K stored [b][h][s][dk]; V stored transposed [b][h][dk][s] with the
// in-block-of-32 key permutation (R9, NO R14 slot-XOR) so flash's PV
// A-fragment is one contiguous bf16x8.
// ---------------------------------------------------------------------------
__global__ __launch_bounds__(256) void qkv_kernel(
    const float* __restrict__ x, const bf16_t* __restrict__ Wt,
    const float* __restrict__ bias,
    bf16_t* __restrict__ Q, bf16_t* __restrict__ Kg, bf16_t* __restrict__ Vt)
{
    constexpr int QSTR = 72;   // 144 B row stride: 16B-aligned, conflict-free
    constexpr int XSTR = 72;   // x-slab row stride (bf16): 2-way alias only
    __shared__ bf16_t Xlds[64 * XSTR];     // 9 KB
    __shared__ bf16_t Slds[4][16 * QSTR];  // 9 KB
    const int tid = threadIdx.x;
    const int w = tid >> 6, lane = tid & 63;
    const int ln = lane & 15, quad = lane >> 4;
    const int bid = blockIdx.x;            // 0..2047
    const int t0 = (bid >> 4) * 64;        // 64-token tile (shared by block)
    const int h  = bid & 15;               // this block's head
    const int tw = t0 + w * 16;            // this wave's 16 tokens
    const int b  = t0 >> 11;               // 64-aligned tile never straddles b
    const int s0 = tw & 2047;
    const int bh = b * 16 + h;

    // ---- coalesced x staging: 64 rows x 64 floats (head slice) -> bf16 LDS
#pragma unroll
    for (int i = 0; i < 4; i++) {
        const int fidx = i * 256 + tid;    // float4 index, 0..1023
        const int row = fidx >> 4;         // 0..63 (16 float4 per row)
        const int c4  = fidx & 15;
        float4 u = *(const float4*)&x[(size_t)(t0 + row)*DMODEL + h*DK + c4*4];
        bf16x4 v4;
        v4[0] = (bf16_t)u.x; v4[1] = (bf16_t)u.y;
        v4[2] = (bf16_t)u.z; v4[3] = (bf16_t)u.w;
        *(bf16x4*)&Xlds[row*XSTR + c4*4] = v4;
    }
    __syncthreads();

    // A-fragments from LDS: A[m=ln][k=quad*8+j], k-chunks of 32.
    bf16x8 afrag[2];
#pragma unroll
    for (int kc = 0; kc < 2; kc++)
        afrag[kc] = *(const bf16x8*)&Xlds[(w*16 + ln)*XSTR + kc*32 + quad*8];

#pragma unroll
    for (int p = 0; p < 3; p++) {
#pragma unroll
        for (int nt = 0; nt < 4; nt++) {
            const bf16_t* wp = &Wt[((size_t)((p*16 + h)*64) + nt*16 + ln)*64 + quad*8];
            bf16x8 b0 = *(const bf16x8*)wp;
            bf16x8 b1 = *(const bf16x8*)(wp + 32);
            f32x4 acc = {0.f, 0.f, 0.f, 0.f};
            acc = __builtin_amdgcn_mfma_f32_16x16x32_bf16(afrag[0], b0, acc, 0, 0, 0);
            acc = __builtin_amdgcn_mfma_f32_16x16x32_bf16(afrag[1], b1, acc, 0, 0, 0);
            float bv = bias[(p*16 + h)*64 + nt*16 + ln];
#pragma unroll
            for (int r = 0; r < 4; r++)
                Slds[w][(quad*4 + r)*QSTR + nt*16 + ln] = (bf16_t)(acc[r] + bv);
        }
        if (p < 2) {
            // row-major coalesced writeout: lane -> (row=lane>>2, col=(lane&3)*16)
            bf16_t* dst = (p == 0) ? Q : Kg;
            const int row = lane >> 2, c = (lane & 3) * 16;
            bf16_t* dp = &dst[((size_t)bh*SEQ + s0 + row)*DK + c];
            *(uint4*)dp       = *(const uint4*)&Slds[w][row*QSTR + c];
            *(uint4*)(dp + 8) = *(const uint4*)&Slds[w][row*QSTR + c + 8];
        } else {
            // V^T writeout: lane = e (0..63), pack 16 tokens (column), with
            // the in-block-of-32 permutation (R9, no slot XOR).
            unsigned int packed[8];
#pragma unroll
            for (int i = 0; i < 8; i++) {
                unsigned short lo = __builtin_bit_cast(unsigned short, Slds[w][(2*i  )*QSTR + lane]);
                unsigned short hi = __builtin_bit_cast(unsigned short, Slds[w][(2*i+1)*QSTR + lane]);
                packed[i] = (unsigned)lo | ((unsigned)hi << 16);
            }
            const int base32 = s0 & ~31;          // 32-key block base
            const int pr = (s0 >> 4) & 1;         // which 16-half of the block
            unsigned* vp32 = (unsigned*)&Vt[((size_t)bh*DK + lane)*SEQ + base32];
#pragma unroll
            for (int i2 = 0; i2 < 4; i2++) {
                uint2 u; u.x = packed[2*i2]; u.y = packed[2*i2 + 1];
                *(uint2*)(vp32 + i2*4 + pr*2) = u;
            }
        }
    }
}

// ---------------------------------------------------------------------------
// Kernel 2: flash attention.  R15 = exact revert to the R13 configuration
// measured at 75.3us (R6 bench): block = 4 waves / 128 queries, 64-key
// chunks, LDS 32KB, VGPR 64, zero scratch.  R14's 2-wave/32-key variant was
// NEUTRAL-NEGATIVE (84us): waves/CU stayed 16 (register-capped at 128
// unified regs/wave = 4 waves/SIMD), so halving the block only doubled
// barrier count.  Lesson: flash TLP is register-capped; keep this shape.
// ---------------------------------------------------------------------------
__global__ __launch_bounds__(256, 4) void flash_kernel(
    const bf16_t* __restrict__ Q, const bf16_t* __restrict__ Kg,
    const bf16_t* __restrict__ Vt, bf16_t* __restrict__ O)
{
    __shared__ union {
        struct { bf16_t K[2][64*64]; bf16_t V[2][64*64]; } kv;  // 32 KB
        bf16_t O[4][32 * 72];        // epilogue reuse (after barrier)
    } sh;

    const int tid = threadIdx.x;
    const int w = tid >> 6, lane = tid & 63;
    const int ln = lane & 15, quad = lane >> 4;
    // XCD swizzle: all 16 q-tiles of one bh on one XCD; 8 bh per XCD -> K/V
    // working set 4MB = L2 size.
    const int bid = blockIdx.x;
    const int xcd = bid & 7;
    const int j   = bid >> 3;            // 0..127
    const int bh  = xcd * 8 + (j & 7);   // 0..63
    const int qt  = j >> 3;              // 0..15
    const int q0 = qt * 128 + w * 32;

    const bf16_t* kbase = &Kg[(size_t)bh * SEQ * DK];
    const bf16_t* vbase = &Vt[(size_t)bh * DK * SEQ];

    // staging coords: each wave covers rows w*16..w*16+15 (2 issues of 8 rows)
    const int lrow = lane >> 3;              // 0..7
    const int swz  = ((lane & 7) ^ lrow) * 8; // swizzled element offset in row

    auto stage = [&](int ci, int buf) {
#pragma unroll
        for (int jj = 0; jj < 2; jj++) {
            const int r = w*16 + jj*8 + lrow;           // tile row, r&7 == lrow
            async_ld16(&kbase[(size_t)(ci*64 + r)*DK + swz],
                       &sh.kv.K[buf][(w*16 + jj*8)*64]);
            async_ld16(&vbase[(size_t)r*SEQ + ci*64 + swz],
                       &sh.kv.V[buf][(w*16 + jj*8)*64]);
        }
    };

    // Resident Q B-fragments: B[k=d=quad*8+j][n=i=ln] = Q[i][d]
    bf16x8 qfrag[2][2];
#pragma unroll
    for (int st = 0; st < 2; st++)
#pragma unroll
        for (int kc = 0; kc < 2; kc++)
            qfrag[st][kc] = *(const bf16x8*)
                &Q[((size_t)bh*SEQ + q0 + st*16 + ln)*DK + kc*32 + quad*8];

    f32x4 o[2][4];
#pragma unroll
    for (int st = 0; st < 2; st++)
#pragma unroll
        for (int dt = 0; dt < 4; dt++)
            o[st][dt] = (f32x4){0.f, 0.f, 0.f, 0.f};
    float l_[2] = {0.f, 0.f};

    // per-lane swizzle constants for fragment reads
    const int s7  = ln & 7;
    const int kc0 = (quad ^ s7) * 8;        // QKT ka0 chunk offset; ka1 = kc0^32

    constexpr int NC = SEQ / 64;
    stage(0, 0);

#pragma unroll 2
    for (int ci = 0; ci < NC; ci++) {
        // chunk-ci loads were issued a full compute-section ago
        asm volatile("s_waitcnt vmcnt(0)" ::: "memory");
        __syncthreads();
        if (ci + 1 < NC) stage(ci + 1, (ci + 1) & 1);

        const bf16_t* Kb = sh.kv.K[ci & 1];
        const bf16_t* Vb = sh.kv.V[ci & 1];

        // S^T = K * Q^T : rows = keys, cols = queries
        f32x4 sfrag[2][4];
#pragma unroll
        for (int kt = 0; kt < 4; kt++) {
            const int kr = (kt*16 + ln) * 64;
            bf16x8 ka0 = *(const bf16x8*)&Kb[kr + kc0];
            bf16x8 ka1 = *(const bf16x8*)&Kb[kr + (kc0 ^ 32)];
#pragma unroll
            for (int st = 0; st < 2; st++) {
                f32x4 acc = {0.f, 0.f, 0.f, 0.f};
                acc = __builtin_amdgcn_mfma_f32_16x16x32_bf16(ka0, qfrag[st][0], acc, 0, 0, 0);
                acc = __builtin_amdgcn_mfma_f32_16x16x32_bf16(ka1, qfrag[st][1], acc, 0, 0, 0);
                sfrag[st][kt] = acc;
            }
        }

        // P = exp2(S^T); l += per-lane sums (VALU); perm-pack into K=32
        // B-fragments (permuted k-axis: slot (quad,j) <-> key
        // (2kt2+(j>>2))*16 + quad*4 + (j&3) -- all lane-local).
        bf16x8 pfrag[2][2];
#pragma unroll
        for (int st = 0; st < 2; st++) {
            float sum = 0.f;
            unsigned pk[8];
#pragma unroll
            for (int kt = 0; kt < 4; kt++) {
                float e0 = FAST_EXP2(sfrag[st][kt][0]);
                float e1 = FAST_EXP2(sfrag[st][kt][1]);
                float e2 = FAST_EXP2(sfrag[st][kt][2]);
                float e3 = FAST_EXP2(sfrag[st][kt][3]);
                sum += (e0 + e1) + (e2 + e3);
                unsigned u0 = __builtin_bit_cast(unsigned, e0);
                unsigned u1 = __builtin_bit_cast(unsigned, e1);
                unsigned u2 = __builtin_bit_cast(unsigned, e2);
                unsigned u3 = __builtin_bit_cast(unsigned, e3);
                pk[2*kt]     = __builtin_amdgcn_perm(u1, u0, 0x07060302);
                pk[2*kt + 1] = __builtin_amdgcn_perm(u3, u2, 0x07060302);
            }
            l_[st] += sum;
            uint4 lo; lo.x = pk[0]; lo.y = pk[1]; lo.z = pk[2]; lo.w = pk[3];
            uint4 hi; hi.x = pk[4]; hi.y = pk[5]; hi.z = pk[6]; hi.w = pk[7];
            pfrag[st][0] = __builtin_bit_cast(bf16x8, lo);
            pfrag[st][1] = __builtin_bit_cast(bf16x8, hi);
        }

        // O^T += V^T * P^T (16x16x32, permuted k; V pre-permuted in global
        // so each A-fragment is ONE contiguous b128 at group kt2*4+quad)
        __builtin_amdgcn_s_setprio(1);
#pragma unroll
        for (int kt2 = 0; kt2 < 2; kt2++) {
#pragma unroll
            for (int dt = 0; dt < 4; dt++) {
                const int vr = (dt*16 + ln) * 64;
                bf16x8 va = *(const bf16x8*)&Vb[vr + (((kt2*4 + quad) ^ s7) * 8)];
                o[0][dt] = __builtin_amdgcn_mfma_f32_16x16x32_bf16(
                    va, pfrag[0][kt2], o[0][dt], 0, 0, 0);
                o[1][dt] = __builtin_amdgcn_mfma_f32_16x16x32_bf16(
                    va, pfrag[1][kt2], o[1][dt], 0, 0, 0);
            }
        }
        __builtin_amdgcn_s_setprio(0);
    }

    // epilogue: reduce l across quads, normalize, transpose via LDS (reuses
    // the K/V buffers -- barrier first), coalesced store
    __syncthreads();
#pragma unroll
    for (int st = 0; st < 2; st++) {
        float l = l_[st];
        l += __shfl_xor(l, 16);
        l += __shfl_xor(l, 32);
        float rl = 1.0f / l;
#pragma unroll
        for (int dt = 0; dt < 4; dt++)
#pragma unroll
            for (int r = 0; r < 4; r++)
                sh.O[w][(st*16 + ln)*72 + dt*16 + quad*4 + r] =
                    (bf16_t)(o[st][dt][r] * rl);
    }
    const int token = lane >> 1, half = lane & 1;
    const int b = bh >> 4, h = bh & 15;
    const size_t s = (size_t)q0 + token;
    bf16_t* op = &O[(((size_t)b*SEQ + s)*NHEADS + h)*DK + half*32];
#pragma unroll
    for (int k2 = 0; k2 < 4; k2++)
        *(uint4*)(op + k2*8) = *(const uint4*)&sh.O[w][token*72 + half*32 + k2*8];
}

// ---------------------------------------------------------------------------
// Kernel 3: residual + LayerNorm.  One wave per token.
// ---------------------------------------------------------------------------
__global__ __launch_bounds__(256) void ln_kernel(
    const bf16_t* __restrict__ O, const float* __restrict__ x,
    const float* __restrict__ gamma, const float* __restrict__ beta,
    float* __restrict__ out)
{
    const int tid = threadIdx.x;
    const int w = tid >> 6, lane = tid & 63;
    const size_t t = (size_t)blockIdx.x * 4 + w;
    const int d0 = lane * 16;
    const bf16_t* op = &O[t*DMODEL + d0];
    const float* xp = &x[t*DMODEL + d0];

    bf16x8 oa = *(const bf16x8*)op;
    bf16x8 ob = *(const bf16x8*)(op + 8);
    float xs[16];
    ((float4*)xs)[0] = *(const float4*)(xp);
    ((float4*)xs)[1] = *(const float4*)(xp + 4);
    ((float4*)xs)[2] = *(const float4*)(xp + 8);
    ((float4*)xs)[3] = *(const float4*)(xp + 12);

    float yv[16];
    float sum = 0.f, sq = 0.f;
#pragma unroll
    for (int j = 0; j < 16; j++) {
        float ov = (j < 8) ? (float)oa[j] : (float)ob[j - 8];
        yv[j] = ov + xs[j];
        sum += yv[j];
        sq += yv[j] * yv[j];
    }
#pragma unroll
    for (int off = 1; off < 64; off <<= 1) {
        sum += __shfl_xor(sum, off);
        sq  += __shfl_xor(sq, off);
    }
    float mean = sum * (1.0f / DMODEL);
    float var = sq * (1.0f / DMODEL) - mean * mean;
    float rstd = rsqrtf(var + 1e-5f);

    float gs[16], bs[16];
    ((float4*)gs)[0] = *(const float4*)&gamma[d0];
    ((float4*)gs)[1] = *(const float4*)&gamma[d0 + 4];
    ((float4*)gs)[2] = *(const float4*)&gamma[d0 + 8];
    ((float4*)gs)[3] = *(const float4*)&gamma[d0 + 12];
    ((float4*)bs)[0] = *(const float4*)&beta[d0];
    ((float4*)bs)[1] = *(const float4*)&beta[d0 + 4];
    ((float4*)bs)[2] = *(const float4*)&beta[d0 + 8];
    ((float4*)bs)[3] = *(const float4*)&beta[d0 + 12];

    float res[16];
#pragma unroll
    for (int j = 0; j < 16; j++)
        res[j] = (yv[j] - mean) * rstd * gs[j] + bs[j];
    float* outp = &out[t*DMODEL + d0];
    *(float4*)(outp)      = *(float4*)&res[0];
    *(float4*)(outp + 4)  = *(float4*)&res[4];
    *(float4*)(outp + 8)  = *(float4*)&res[8];
    *(float4*)(outp + 12) = *(float4*)&res[12];
}

// ---------------------------------------------------------------------------
extern "C" void kernel_launch(void* const* d_in, const int* in_sizes, int n_in,
                              void* d_out, int out_size, void* d_ws, size_t ws_size,
                              hipStream_t stream) {
    const float* x     = (const float*)d_in[0];
    const float* Wq    = (const float*)d_in[1];
    const float* Wk    = (const float*)d_in[2];
    const float* Wv    = (const float*)d_in[3];
    const float* bq    = (const float*)d_in[4];
    const float* bk    = (const float*)d_in[5];
    const float* bv    = (const float*)d_in[6];
    const float* gamma = (const float*)d_in[7];
    const float* beta  = (const float*)d_in[8];

    char* ws = (char*)d_ws;
    bf16_t* Wt   = (bf16_t*)(ws + WT_OFF);
    float*  bias = (float*)(ws + BIAS_OFF);
    bf16_t* Qb   = (bf16_t*)(ws + Q_OFF);
    bf16_t* Kb   = (bf16_t*)(ws + K_OFF);
    bf16_t* Vtb  = (bf16_t*)(ws + VT_OFF);
    bf16_t* Ob   = (bf16_t*)(ws + O_OFF);

    prep_kernel<<<768, 256, 0, stream>>>(Wq, Wk, Wv, bq, bk, bv, Wt, bias);
    qkv_kernel<<<(NTOK/64)*NHEADS, 256, 0, stream>>>(x, Wt, bias, Qb, Kb, Vtb);
    flash_kernel<<<BATCH*NHEADS*(SEQ/128), 256, 0, stream>>>(Qb, Kb, Vtb, Ob);
    ln_kernel<<<NTOK/4, 256, 0, stream>>>(Ob, x, gamma, beta, (float*)d_out);
}

// Round 10
// 205.068 us; speedup vs baseline: 1.1047x; 1.0654x over previous
//
#include <hip/hip_runtime.h>
#include <math.h>

typedef __bf16 bf16_t;
typedef __bf16 bf16x8 __attribute__((ext_vector_type(8)));
typedef __bf16 bf16x4 __attribute__((ext_vector_type(4)));
typedef short short4v __attribute__((ext_vector_type(4)));
typedef float f32x4 __attribute__((ext_vector_type(4)));

#define LOG2E 1.4426950408889634f

#if __has_builtin(__builtin_amdgcn_exp2f)
#define FAST_EXP2(x) __builtin_amdgcn_exp2f(x)
#else
#define FAST_EXP2(x) exp2f(x)
#endif

#define GLOBAL_AS __attribute__((address_space(1)))
#define LDS_AS    __attribute__((address_space(3)))

// async 16B/lane global->LDS DMA: lane i's data lands at ldsbase + i*16.
__device__ __forceinline__ void async_ld16(const void* g, void* l) {
    __builtin_amdgcn_global_load_lds((const GLOBAL_AS void*)g,
                                     (LDS_AS void*)l, 16, 0, 0);
}

constexpr int BATCH = 4;
constexpr int SEQ = 2048;
constexpr int NHEADS = 16;
constexpr int DK = 64;
constexpr int DMODEL = 1024;
constexpr int NTOK = BATCH * SEQ;  // 8192

// workspace layout (bytes)
constexpr size_t WT_OFF   = 0;                                   // 3*16*64*64 bf16
constexpr size_t BIAS_OFF = WT_OFF + (size_t)3*16*64*64*2;
constexpr size_t Q_OFF    = BIAS_OFF + (size_t)3*16*64*4;
constexpr size_t QSZ      = (size_t)BATCH*NHEADS*SEQ*DK*2;
constexpr size_t K_OFF    = Q_OFF + QSZ;
constexpr size_t VT_OFF   = K_OFF + QSZ;
constexpr size_t O_OFF    = VT_OFF + QSZ;

// ---------------------------------------------------------------------------
// Kernel 0: weight prep.  Wt[p][h][e][d] = W_p[h][d][e].
// Q path additionally scaled by LOG2E/8 so flash can exp2() raw MFMA output.
// ---------------------------------------------------------------------------
__global__ __launch_bounds__(256) void prep_kernel(
    const float* __restrict__ Wq, const float* __restrict__ Wk,
    const float* __restrict__ Wv, const float* __restrict__ bq,
    const float* __restrict__ bk, const float* __restrict__ bv,
    bf16_t* __restrict__ Wt, float* __restrict__ bias)
{
    const float QS = 0.125f * LOG2E;
    int i = blockIdx.x * 256 + threadIdx.x;
    if (i < 3*16*64*64) {
        int d = i & 63, e = (i >> 6) & 63, h = (i >> 12) & 15, p = i >> 16;
        const float* W = (p == 0) ? Wq : (p == 1) ? Wk : Wv;
        float v = W[(h*64 + d)*64 + e] * ((p == 0) ? QS : 1.0f);
        Wt[i] = (bf16_t)v;
    }
    if (i < 3*16*64) {
        int e = i & 63, h = (i >> 6) & 15, p = i >> 10;
        const float* bb = (p == 0) ? bq : (p == 1) ? bk : bv;
        bias[i] = bb[h*64 + e] * ((p == 0) ? QS : 1.0f);
    }
}

// ---------------------------------------------------------------------------
// Kernel 1: QKV projection.  Block = 64 tokens x 1 head (R15 TLP shape,
// grid 2048, 8 blocks/CU).
// R16/R17: coalesced V^T writeout.  Each lane's p=2 acc[0..3] maps to 4
// CONSECUTIVE permuted key slots (elem = (w>>1)*32 + quad*8 + (w&1)*4 + r
// for token w*16+quad*4+r -- identical layout to the proven R9 scattered
// path), written as b64s into a shared 64x64 LDS V-tile (stride 68 bf16),
// then copied out 64 rows x 128B fully coalesced.
// R17 FIX: copy-out dst uses (t0 & 2047) -- R16 used global t0, misplacing
// V for batches 1..3 (absmax 0.41).  Q/K always masked correctly.
// Global V format unchanged: [b][h][dk][s] with R9 in-block-of-32 key
// permutation, exactly what flash's single-b128 PV fragments expect.
// ---------------------------------------------------------------------------
__global__ __launch_bounds__(256) void qkv_kernel(
    const float* __restrict__ x, const bf16_t* __restrict__ Wt,
    const float* __restrict__ bias,
    bf16_t* __restrict__ Q, bf16_t* __restrict__ Kg, bf16_t* __restrict__ Vt)
{
    constexpr int QSTR = 72;   // 144 B row stride: 16B-aligned, conflict-free
    constexpr int XSTR = 72;   // x-slab row stride (bf16): 2-way alias only
    constexpr int VSTR = 68;   // V-tile row stride (bf16): 136B, 8B-aligned
    __shared__ union {
        bf16_t X[64 * XSTR];               // 9216 B (staging phase)
        bf16_t V[64 * VSTR];               // 8704 B (writeout phase)
    } xv;
    __shared__ bf16_t Slds[4][16 * QSTR];  // 9 KB
    const int tid = threadIdx.x;
    const int w = tid >> 6, lane = tid & 63;
    const int ln = lane & 15, quad = lane >> 4;
    const int bid = blockIdx.x;            // 0..2047
    const int t0 = (bid >> 4) * 64;        // 64-token tile (shared by block)
    const int h  = bid & 15;               // this block's head
    const int tw = t0 + w * 16;            // this wave's 16 tokens
    const int b  = t0 >> 11;               // 64-aligned tile never straddles b
    const int s0 = tw & 2047;
    const int sb = t0 & 2047;              // tile base within the sequence
    const int bh = b * 16 + h;

    // ---- coalesced x staging: 64 rows x 64 floats (head slice) -> bf16 LDS
#pragma unroll
    for (int i = 0; i < 4; i++) {
        const int fidx = i * 256 + tid;    // float4 index, 0..1023
        const int row = fidx >> 4;         // 0..63 (16 float4 per row)
        const int c4  = fidx & 15;
        float4 u = *(const float4*)&x[(size_t)(t0 + row)*DMODEL + h*DK + c4*4];
        bf16x4 v4;
        v4[0] = (bf16_t)u.x; v4[1] = (bf16_t)u.y;
        v4[2] = (bf16_t)u.z; v4[3] = (bf16_t)u.w;
        *(bf16x4*)&xv.X[row*XSTR + c4*4] = v4;
    }
    __syncthreads();

    // A-fragments from LDS: A[m=ln][k=quad*8+j], k-chunks of 32.
    bf16x8 afrag[2];
#pragma unroll
    for (int kc = 0; kc < 2; kc++)
        afrag[kc] = *(const bf16x8*)&xv.X[(w*16 + ln)*XSTR + kc*32 + quad*8];
    __syncthreads();   // all waves done with X; its space becomes the V-tile

#pragma unroll
    for (int p = 0; p < 3; p++) {
#pragma unroll
        for (int nt = 0; nt < 4; nt++) {
            const bf16_t* wp = &Wt[((size_t)((p*16 + h)*64) + nt*16 + ln)*64 + quad*8];
            bf16x8 b0 = *(const bf16x8*)wp;
            bf16x8 b1 = *(const bf16x8*)(wp + 32);
            f32x4 acc = {0.f, 0.f, 0.f, 0.f};
            acc = __builtin_amdgcn_mfma_f32_16x16x32_bf16(afrag[0], b0, acc, 0, 0, 0);
            acc = __builtin_amdgcn_mfma_f32_16x16x32_bf16(afrag[1], b1, acc, 0, 0, 0);
            float bv = bias[(p*16 + h)*64 + nt*16 + ln];
            if (p < 2) {
#pragma unroll
                for (int r = 0; r < 4; r++)
                    Slds[w][(quad*4 + r)*QSTR + nt*16 + ln] = (bf16_t)(acc[r] + bv);
            } else {
                // direct permuted V write (R16): token w*16+quad*4+r ->
                // elem (w>>1)*32 + quad*8 + (w&1)*4 + r (r consecutive = b64)
                bf16x4 v4;
                v4[0] = (bf16_t)(acc[0] + bv);
                v4[1] = (bf16_t)(acc[1] + bv);
                v4[2] = (bf16_t)(acc[2] + bv);
                v4[3] = (bf16_t)(acc[3] + bv);
                *(bf16x4*)&xv.V[(nt*16 + ln)*VSTR + (w >> 1)*32 + quad*8 + (w & 1)*4] = v4;
            }
        }
        if (p < 2) {
            // row-major coalesced writeout: lane -> (row=lane>>2, col=(lane&3)*16)
            bf16_t* dst = (p == 0) ? Q : Kg;
            const int row = lane >> 2, c = (lane & 3) * 16;
            bf16_t* dp = &dst[((size_t)bh*SEQ + s0 + row)*DK + c];
            *(uint4*)dp       = *(const uint4*)&Slds[w][row*QSTR + c];
            *(uint4*)(dp + 8) = *(const uint4*)&Slds[w][row*QSTR + c + 8];
        }
    }

    // ---- coalesced V copy-out: 64 e-rows x 128B; 4 threads per row
    __syncthreads();
    {
        const int r  = tid >> 2;          // e row 0..63
        const int sg = tid & 3;           // 32B segment
        const unsigned* src = (const unsigned*)&xv.V[r*VSTR] + sg*8;
        unsigned* dst = (unsigned*)&Vt[((size_t)bh*DK + r)*SEQ + sb] + sg*8;
        uint2 a0 = *(const uint2*)(src + 0);
        uint2 a1 = *(const uint2*)(src + 2);
        uint2 a2 = *(const uint2*)(src + 4);
        uint2 a3 = *(const uint2*)(src + 6);
        uint4 o0; o0.x = a0.x; o0.y = a0.y; o0.z = a1.x; o0.w = a1.y;
        uint4 o1; o1.x = a2.x; o1.y = a2.y; o1.z = a3.x; o1.w = a3.y;
        *(uint4*)(dst)     = o0;
        *(uint4*)(dst + 4) = o1;
    }
}

// ---------------------------------------------------------------------------
// Kernel 2: flash attention.  Unchanged from R15 = the proven 75.3us config
// (R6 bench): block = 4 waves / 128 queries, 64-key chunks, LDS 32KB,
// VGPR 64, zero scratch, permuted-V single-b128 PV, setprio around PV.
// R14 lesson: flash TLP is register-capped at 16 waves/CU; keep this shape.
// ---------------------------------------------------------------------------
__global__ __launch_bounds__(256, 4) void flash_kernel(
    const bf16_t* __restrict__ Q, const bf16_t* __restrict__ Kg,
    const bf16_t* __restrict__ Vt, bf16_t* __restrict__ O)
{
    __shared__ union {
        struct { bf16_t K[2][64*64]; bf16_t V[2][64*64]; } kv;  // 32 KB
        bf16_t O[4][32 * 72];        // epilogue reuse (after barrier)
    } sh;

    const int tid = threadIdx.x;
    const int w = tid >> 6, lane = tid & 63;
    const int ln = lane & 15, quad = lane >> 4;
    // XCD swizzle: all 16 q-tiles of one bh on one XCD; 8 bh per XCD -> K/V
    // working set 4MB = L2 size.
    const int bid = blockIdx.x;
    const int xcd = bid & 7;
    const int j   = bid >> 3;            // 0..127
    const int bh  = xcd * 8 + (j & 7);   // 0..63
    const int qt  = j >> 3;              // 0..15
    const int q0 = qt * 128 + w * 32;

    const bf16_t* kbase = &Kg[(size_t)bh * SEQ * DK];
    const bf16_t* vbase = &Vt[(size_t)bh * DK * SEQ];

    // staging coords: each wave covers rows w*16..w*16+15 (2 issues of 8 rows)
    const int lrow = lane >> 3;              // 0..7
    const int swz  = ((lane & 7) ^ lrow) * 8; // swizzled element offset in row

    auto stage = [&](int ci, int buf) {
#pragma unroll
        for (int jj = 0; jj < 2; jj++) {
            const int r = w*16 + jj*8 + lrow;           // tile row, r&7 == lrow
            async_ld16(&kbase[(size_t)(ci*64 + r)*DK + swz],
                       &sh.kv.K[buf][(w*16 + jj*8)*64]);
            async_ld16(&vbase[(size_t)r*SEQ + ci*64 + swz],
                       &sh.kv.V[buf][(w*16 + jj*8)*64]);
        }
    };

    // Resident Q B-fragments: B[k=d=quad*8+j][n=i=ln] = Q[i][d]
    bf16x8 qfrag[2][2];
#pragma unroll
    for (int st = 0; st < 2; st++)
#pragma unroll
        for (int kc = 0; kc < 2; kc++)
            qfrag[st][kc] = *(const bf16x8*)
                &Q[((size_t)bh*SEQ + q0 + st*16 + ln)*DK + kc*32 + quad*8];

    f32x4 o[2][4];
#pragma unroll
    for (int st = 0; st < 2; st++)
#pragma unroll
        for (int dt = 0; dt < 4; dt++)
            o[st][dt] = (f32x4){0.f, 0.f, 0.f, 0.f};
    float l_[2] = {0.f, 0.f};

    // per-lane swizzle constants for fragment reads
    const int s7  = ln & 7;
    const int kc0 = (quad ^ s7) * 8;        // QKT ka0 chunk offset; ka1 = kc0^32

    constexpr int NC = SEQ / 64;
    stage(0, 0);

#pragma unroll 2
    for (int ci = 0; ci < NC; ci++) {
        // chunk-ci loads were issued a full compute-section ago
        asm volatile("s_waitcnt vmcnt(0)" ::: "memory");
        __syncthreads();
        if (ci + 1 < NC) stage(ci + 1, (ci + 1) & 1);

        const bf16_t* Kb = sh.kv.K[ci & 1];
        const bf16_t* Vb = sh.kv.V[ci & 1];

        // S^T = K * Q^T : rows = keys, cols = queries
        f32x4 sfrag[2][4];
#pragma unroll
        for (int kt = 0; kt < 4; kt++) {
            const int kr = (kt*16 + ln) * 64;
            bf16x8 ka0 = *(const bf16x8*)&Kb[kr + kc0];
            bf16x8 ka1 = *(const bf16x8*)&Kb[kr + (kc0 ^ 32)];
#pragma unroll
            for (int st = 0; st < 2; st++) {
                f32x4 acc = {0.f, 0.f, 0.f, 0.f};
                acc = __builtin_amdgcn_mfma_f32_16x16x32_bf16(ka0, qfrag[st][0], acc, 0, 0, 0);
                acc = __builtin_amdgcn_mfma_f32_16x16x32_bf16(ka1, qfrag[st][1], acc, 0, 0, 0);
                sfrag[st][kt] = acc;
            }
        }

        // P = exp2(S^T); l += per-lane sums (VALU); perm-pack into K=32
        // B-fragments (permuted k-axis: slot (quad,j) <-> key
        // (2kt2+(j>>2))*16 + quad*4 + (j&3) -- all lane-local).
        bf16x8 pfrag[2][2];
#pragma unroll
        for (int st = 0; st < 2; st++) {
            float sum = 0.f;
            unsigned pk[8];
#pragma unroll
            for (int kt = 0; kt < 4; kt++) {
                float e0 = FAST_EXP2(sfrag[st][kt][0]);
                float e1 = FAST_EXP2(sfrag[st][kt][1]);
                float e2 = FAST_EXP2(sfrag[st][kt][2]);
                float e3 = FAST_EXP2(sfrag[st][kt][3]);
                sum += (e0 + e1) + (e2 + e3);
                unsigned u0 = __builtin_bit_cast(unsigned, e0);
                unsigned u1 = __builtin_bit_cast(unsigned, e1);
                unsigned u2 = __builtin_bit_cast(unsigned, e2);
                unsigned u3 = __builtin_bit_cast(unsigned, e3);
                pk[2*kt]     = __builtin_amdgcn_perm(u1, u0, 0x07060302);
                pk[2*kt + 1] = __builtin_amdgcn_perm(u3, u2, 0x07060302);
            }
            l_[st] += sum;
            uint4 lo; lo.x = pk[0]; lo.y = pk[1]; lo.z = pk[2]; lo.w = pk[3];
            uint4 hi; hi.x = pk[4]; hi.y = pk[5]; hi.z = pk[6]; hi.w = pk[7];
            pfrag[st][0] = __builtin_bit_cast(bf16x8, lo);
            pfrag[st][1] = __builtin_bit_cast(bf16x8, hi);
        }

        // O^T += V^T * P^T (16x16x32, permuted k; V pre-permuted in global
        // so each A-fragment is ONE contiguous b128 at group kt2*4+quad)
        __builtin_amdgcn_s_setprio(1);
#pragma unroll
        for (int kt2 = 0; kt2 < 2; kt2++) {
#pragma unroll
            for (int dt = 0; dt < 4; dt++) {
                const int vr = (dt*16 + ln) * 64;
                bf16x8 va = *(const bf16x8*)&Vb[vr + (((kt2*4 + quad) ^ s7) * 8)];
                o[0][dt] = __builtin_amdgcn_mfma_f32_16x16x32_bf16(
                    va, pfrag[0][kt2], o[0][dt], 0, 0, 0);
                o[1][dt] = __builtin_amdgcn_mfma_f32_16x16x32_bf16(
                    va, pfrag[1][kt2], o[1][dt], 0, 0, 0);
            }
        }
        __builtin_amdgcn_s_setprio(0);
    }

    // epilogue: reduce l across quads, normalize, transpose via LDS (reuses
    // the K/V buffers -- barrier first), coalesced store
    __syncthreads();
#pragma unroll
    for (int st = 0; st < 2; st++) {
        float l = l_[st];
        l += __shfl_xor(l, 16);
        l += __shfl_xor(l, 32);
        float rl = 1.0f / l;
#pragma unroll
        for (int dt = 0; dt < 4; dt++)
#pragma unroll
            for (int r = 0; r < 4; r++)
                sh.O[w][(st*16 + ln)*72 + dt*16 + quad*4 + r] =
                    (bf16_t)(o[st][dt][r] * rl);
    }
    const int token = lane >> 1, half = lane & 1;
    const int b = bh >> 4, h = bh & 15;
    const size_t s = (size_t)q0 + token;
    bf16_t* op = &O[(((size_t)b*SEQ + s)*NHEADS + h)*DK + half*32];
#pragma unroll
    for (int k2 = 0; k2 < 4; k2++)
        *(uint4*)(op + k2*8) = *(const uint4*)&sh.O[w][token*72 + half*32 + k2*8];
}

// ---------------------------------------------------------------------------
// Kernel 3: residual + LayerNorm.  One wave per token.
// ---------------------------------------------------------------------------
__global__ __launch_bounds__(256) void ln_kernel(
    const bf16_t* __restrict__ O, const float* __restrict__ x,
    const float* __restrict__ gamma, const float* __restrict__ beta,
    float* __restrict__ out)
{
    const int tid = threadIdx.x;
    const int w = tid >> 6, lane = tid & 63;
    const size_t t = (size_t)blockIdx.x * 4 + w;
    const int d0 = lane * 16;
    const bf16_t* op = &O[t*DMODEL + d0];
    const float* xp = &x[t*DMODEL + d0];

    bf16x8 oa = *(const bf16x8*)op;
    bf16x8 ob = *(const bf16x8*)(op + 8);
    float xs[16];
    ((float4*)xs)[0] = *(const float4*)(xp);
    ((float4*)xs)[1] = *(const float4*)(xp + 4);
    ((float4*)xs)[2] = *(const float4*)(xp + 8);
    ((float4*)xs)[3] = *(const float4*)(xp + 12);

    float yv[16];
    float sum = 0.f, sq = 0.f;
#pragma unroll
    for (int j = 0; j < 16; j++) {
        float ov = (j < 8) ? (float)oa[j] : (float)ob[j - 8];
        yv[j] = ov + xs[j];
        sum += yv[j];
        sq += yv[j] * yv[j];
    }
#pragma unroll
    for (int off = 1; off < 64; off <<= 1) {
        sum += __shfl_xor(sum, off);
        sq  += __shfl_xor(sq, off);
    }
    float mean = sum * (1.0f / DMODEL);
    float var = sq * (1.0f / DMODEL) - mean * mean;
    float rstd = rsqrtf(var + 1e-5f);

    float gs[16], bs[16];
    ((float4*)gs)[0] = *(const float4*)&gamma[d0];
    ((float4*)gs)[1] = *(const float4*)&gamma[d0 + 4];
    ((float4*)gs)[2] = *(const float4*)&gamma[d0 + 8];
    ((float4*)gs)[3] = *(const float4*)&gamma[d0 + 12];
    ((float4*)bs)[0] = *(const float4*)&beta[d0];
    ((float4*)bs)[1] = *(const float4*)&beta[d0 + 4];
    ((float4*)bs)[2] = *(const float4*)&beta[d0 + 8];
    ((float4*)bs)[3] = *(const float4*)&beta[d0 + 12];

    float res[16];
#pragma unroll
    for (int j = 0; j < 16; j++)
        res[j] = (yv[j] - mean) * rstd * gs[j] + bs[j];
    float* outp = &out[t*DMODEL + d0];
    *(float4*)(outp)      = *(float4*)&res[0];
    *(float4*)(outp + 4)  = *(float4*)&res[4];
    *(float4*)(outp + 8)  = *(float4*)&res[8];
    *(float4*)(outp + 12) = *(float4*)&res[12];
}

// ---------------------------------------------------------------------------
extern "C" void kernel_launch(void* const* d_in, const int* in_sizes, int n_in,
                              void* d_out, int out_size, void* d_ws, size_t ws_size,
                              hipStream_t stream) {
    const float* x     = (const float*)d_in[0];
    const float* Wq    = (const float*)d_in[1];
    const float* Wk    = (const float*)d_in[2];
    const float* Wv    = (const float*)d_in[3];
    const float* bq    = (const float*)d_in[4];
    const float* bk    = (const float*)d_in[5];
    const float* bv    = (const float*)d_in[6];
    const float* gamma = (const float*)d_in[7];
    const float* beta  = (const float*)d_in[8];

    char* ws = (char*)d_ws;
    bf16_t* Wt   = (bf16_t*)(ws + WT_OFF);
    float*  bias = (float*)(ws + BIAS_OFF);
    bf16_t* Qb   = (bf16_t*)(ws + Q_OFF);
    bf16_t* Kb   = (bf16_t*)(ws + K_OFF);
    bf16_t* Vtb  = (bf16_t*)(ws + VT_OFF);
    bf16_t* Ob   = (bf16_t*)(ws + O_OFF);

    prep_kernel<<<768, 256, 0, stream>>>(Wq, Wk, Wv, bq, bk, bv, Wt, bias);
    qkv_kernel<<<(NTOK/64)*NHEADS, 256, 0, stream>>>(x, Wt, bias, Qb, Kb, Vtb);
    flash_kernel<<<BATCH*NHEADS*(SEQ/128), 256, 0, stream>>>(Qb, Kb, Vtb, Ob);
    ln_kernel<<<NTOK/4, 256, 0, stream>>>(Ob, x, gamma, beta, (float*)d_out);
}